// Round 1
// baseline (183.074 us; speedup 1.0000x reference)
//
#include <hip/hip_runtime.h>

// Problem constants (hardcoded; spatial_shapes = [[4,8]]*4)
//  bs=64, nq=64, E=256, Hn=8, dh=32, L=4, P=16, BEV=2, Pb=32
//  qb=128 collapses to 64. OFF col (h,f,c)=h*256+2f+c; rp level = f&3;
//  image level = f>>5; attn key = f; output pairs (2q,2q+1) -> rows pj/pj+32.
//
// ws: [0,1M) Wtb bf16 [2048][256] | [1M,3M) Qb bf16 [4096][256]
//     [3M,5M) Khb bf16 [4096][256]
//
// mega3 (this round): M-split — each wave owns q-strip [16*wave, +16).
//  * B-frags direct from Wtb (L2): Bsl LDS staging + 8 barriers removed.
//  * softmax probs kept in registers, shfl'd to scatter: attLb removed.
//  * scatter/cvt/AV operate on wave-private Am strip: no barriers needed.
//  => LDS 65024 -> 44544 (3 blocks/CU), barriers 12 -> 1.

typedef short  s16x8 __attribute__((ext_vector_type(8)));
typedef short  s16x4 __attribute__((ext_vector_type(4)));
typedef float  f32x4 __attribute__((ext_vector_type(4)));

__device__ __forceinline__ unsigned short f2bf(float f) {
    union { float f; unsigned u; } v; v.f = f;
    unsigned r = v.u + 0x7FFFu + ((v.u >> 16) & 1u);   // RNE
    return (unsigned short)(r >> 16);
}
__device__ __forceinline__ float bf2f(unsigned short u) {
    return __uint_as_float(((unsigned)u) << 16);
}

// ---------------------------------------------------------------------------
// prep: [0,512) W transpose f32->bf16 ; [512,1536) query->Qb ;
//       [1536,2560) key_hist->Khb   (unchanged from verified baseline)
// ---------------------------------------------------------------------------
__global__ __launch_bounds__(256) void prep(
    const float* __restrict__ W, const float* __restrict__ query,
    const float* __restrict__ key_hist,
    short* __restrict__ Wtb, short* __restrict__ Qb, short* __restrict__ Khb)
{
    __shared__ float s[32][33];
    const int bx = blockIdx.x, t = threadIdx.x;
    if (bx < 512) {
        const int n0 = (bx & 63) * 32, k0 = (bx >> 6) * 32;
        const int c = t & 31, r0 = t >> 5;
        #pragma unroll
        for (int p = 0; p < 4; ++p) {
            const int r = r0 + p * 8;
            s[r][c] = W[(size_t)(k0 + r) * 2048 + n0 + c];
        }
        __syncthreads();
        #pragma unroll
        for (int p = 0; p < 4; ++p) {
            const int r = r0 + p * 8;
            Wtb[(size_t)(n0 + r) * 256 + k0 + c] = (short)f2bf(s[c][r]);
        }
    } else {
        const int j = bx - 512;
        const bool isK = j >= 1024;
        const float* src = isK ? key_hist : query;
        short* dst = isK ? Khb : Qb;
        const int i4 = ((j & 1023) * 256 + t) * 4;
        const float4 v = *(const float4*)(src + i4);
        s16x4 o;
        o.x = (short)f2bf(v.x); o.y = (short)f2bf(v.y);
        o.z = (short)f2bf(v.z); o.w = (short)f2bf(v.w);
        *(s16x4*)(dst + i4) = o;
    }
}

// ---------------------------------------------------------------------------
// mega3: one block per (h,b). LDS 44544 B -> 3 blocks/CU. ONE barrier.
// ---------------------------------------------------------------------------
__global__ __launch_bounds__(256, 3) void mega3(
    const float* __restrict__ query, const float* __restrict__ value_hist,
    const float* __restrict__ refp,
    const short* __restrict__ Qb, const short* __restrict__ Khb,
    const short* __restrict__ Wtb, const float* __restrict__ bias,
    float* __restrict__ out)
{
    const int h = blockIdx.x, b = blockIdx.y;
    const int t = threadIdx.x, lane = t & 63, wave = t >> 6;
    const int quad = lane >> 4, col = lane & 15;
    const int wq = wave * 16;

    __shared__ __align__(16) short VTl[32 * 136];   // V^T [d][p], 8704 B
    __shared__ __align__(16) float rpsL[512];       // refp rows, 2048 B
    __shared__ __align__(16) float Am[64 * 132];    // scatter acc, 33792 B

    // ============ Phase 0: stage VTl + rps; zero own Am strip ============
    {   // VTl[d][p]: values = [query rows | value_hist rows] h-slice, transposed
        const int p = t >> 1, hf = (t & 1) * 16;
        const float* src = ((p < 64) ? query : value_hist) +
                           (size_t)(b * 64 + (p & 63)) * 256 + h * 32 + hf;
        #pragma unroll
        for (int u = 0; u < 4; ++u) {
            const float4 v = *(const float4*)(src + 4 * u);
            VTl[(hf + 4 * u + 0) * 136 + p] = (short)f2bf(v.x);
            VTl[(hf + 4 * u + 1) * 136 + p] = (short)f2bf(v.y);
            VTl[(hf + 4 * u + 2) * 136 + p] = (short)f2bf(v.z);
            VTl[(hf + 4 * u + 3) * 136 + p] = (short)f2bf(v.w);
        }
    }
    rpsL[t]       = refp[(size_t)b * 512 + t];
    rpsL[t + 256] = refp[(size_t)b * 512 + t + 256];
    {   // wave-private strip zero (ordered vs own atomics by program order)
        float* strip = &Am[wq * 132];
        #pragma unroll
        for (int u = 0; u < 33; ++u) strip[lane + 64 * u] = 0.f;
    }

    // ============ Phase 2: offsets GEMM, M-split (no LDS, no barriers) =====
    // wave computes q-strip [wq,wq+16) x n' in [0,256): acc[nj], n'=16nj+col.
    f32x4 acc[16];
    #pragma unroll
    for (int nj = 0; nj < 16; ++nj) acc[nj] = f32x4{0.f, 0.f, 0.f, 0.f};
    {
        const short* qrow = Qb + ((size_t)b * 64 + wq + col) * 256 + quad * 8;
        const short* wrow = Wtb + ((size_t)(h * 256 + col)) * 256 + quad * 8;
        for (int kq = 0; kq < 4; ++kq) {
            const s16x8 a0 = *(const s16x8*)(qrow + kq * 64);
            const s16x8 a1 = *(const s16x8*)(qrow + kq * 64 + 32);
            #pragma unroll
            for (int njc = 0; njc < 4; ++njc) {
                s16x8 bf0[4], bf1[4];
                #pragma unroll
                for (int j = 0; j < 4; ++j) {
                    const short* wp = wrow + (size_t)(njc * 4 + j) * 4096 + kq * 64;
                    bf0[j] = *(const s16x8*)(wp);
                    bf1[j] = *(const s16x8*)(wp + 32);
                }
                #pragma unroll
                for (int j = 0; j < 4; ++j) {
                    acc[njc * 4 + j] = __builtin_amdgcn_mfma_f32_16x16x32_bf16(
                        a0, bf0[j], acc[njc * 4 + j], 0, 0, 0);
                    acc[njc * 4 + j] = __builtin_amdgcn_mfma_f32_16x16x32_bf16(
                        a1, bf1[j], acc[njc * 4 + j], 0, 0, 0);
                }
            }
        }
    }

    // ============ Phase 1: logits + softmax -> pro[][] in registers ========
    float pro[8][4];   // pro[t8][r] = attn(q=wq+4quad+r, f=16t8+col)
    {
        const s16x8 aq = *(const s16x8*)(Qb +
            ((size_t)b * 64 + wq + col) * 256 + h * 32 + quad * 8);
        f32x4 lacc[8];
        #pragma unroll
        for (int t8 = 0; t8 < 8; ++t8) {
            const short* src = (t8 < 4)
                ? (Qb  + ((size_t)b * 64 + 16 * t8 + col) * 256)
                : (Khb + ((size_t)b * 64 + 16 * (t8 - 4) + col) * 256);
            const s16x8 bk = *(const s16x8*)(src + h * 32 + quad * 8);
            const f32x4 z = {0.f, 0.f, 0.f, 0.f};
            lacc[t8] = __builtin_amdgcn_mfma_f32_16x16x32_bf16(aq, bk, z, 0, 0, 0);
        }
        #pragma unroll
        for (int r = 0; r < 4; ++r) {
            float m = lacc[0][r];
            #pragma unroll
            for (int t8 = 1; t8 < 8; ++t8) m = fmaxf(m, lacc[t8][r]);
            #pragma unroll
            for (int s = 1; s < 16; s <<= 1) m = fmaxf(m, __shfl_xor(m, s, 64));
            float e[8], ssum = 0.f;
            #pragma unroll
            for (int t8 = 0; t8 < 8; ++t8) {
                e[t8] = __expf(lacc[t8][r] - m); ssum += e[t8];
            }
            #pragma unroll
            for (int s = 1; s < 16; s <<= 1) ssum += __shfl_xor(ssum, s, 64);
            const float inv = 1.0f / ssum;
            #pragma unroll
            for (int t8 = 0; t8 < 8; ++t8) pro[t8][r] = e[t8] * inv;
        }
    }

    // prefetch bias (hides L2 latency under the barrier)
    float bjv[16];
    #pragma unroll
    for (int nj = 0; nj < 16; ++nj) bjv[nj] = bias[h * 256 + 16 * nj + col];

    __syncthreads();   // the ONLY block barrier: VTl + rpsL now visible

    // ============ Phase 3: bilinear scatter into own Am strip ==============
    {
        const int i   = col >> 1;          // f-sub 0..7 ; rp level = i&3
        const int par = col & 1;           // 0: x-coords, 1: y-coords
        #pragma unroll
        for (int nj = 0; nj < 16; ++nj) {
            const int base = (nj >> 2) * 32;        // image level = f>>5
            const int srcl = quad * 16 + 8 * (nj & 1) + i;
            float v[4], p[4];
            #pragma unroll
            for (int r = 0; r < 4; ++r) v[r] = acc[nj][r] + bjv[nj];
            #pragma unroll
            for (int r = 0; r < 4; ++r) p[r] = __shfl_xor(v[r], 1, 64);
            #pragma unroll
            for (int rs = 0; rs < 2; ++rs) {
                const float a0s = __shfl(pro[nj >> 1][rs],     srcl, 64);
                const float a1s = __shfl(pro[nj >> 1][2 + rs], srcl, 64);
                const float a  = par ? a1s : a0s;
                const float ox = par ? p[2 + rs] : v[rs];
                const float oy = par ? v[2 + rs] : p[rs];
                const int ql = 4 * quad + 2 * par + rs;
                const float2 rp = *(const float2*)&rpsL[(wq + ql) * 8 + (i & 3) * 2];
                const float gx = 8.f * (rp.x + ox * 0.125f) - 0.5f;
                const float gy = 4.f * (rp.y + oy * 0.25f) - 0.5f;
                const float x0f = floorf(gx), y0f = floorf(gy);
                const float wx = gx - x0f, wy = gy - y0f;
                const int x0 = (int)x0f, y0 = (int)y0f;
                float* rowW = &Am[(wq + ql) * 132 + base];
                const bool xv0 = (x0 >= 0) && (x0 < 8);
                const bool xv1 = (x0 >= -1) && (x0 < 7);
                const bool yv0 = (y0 >= 0) && (y0 < 4);
                const bool yv1 = (y0 >= -1) && (y0 < 3);
                if (xv0 && yv0) unsafeAtomicAdd(&rowW[y0 * 8 + x0],           a * (1.f - wx) * (1.f - wy));
                if (xv1 && yv0) unsafeAtomicAdd(&rowW[y0 * 8 + x0 + 1],       a * wx * (1.f - wy));
                if (xv0 && yv1) unsafeAtomicAdd(&rowW[(y0 + 1) * 8 + x0],     a * (1.f - wx) * wy);
                if (xv1 && yv1) unsafeAtomicAdd(&rowW[(y0 + 1) * 8 + x0 + 1], a * wx * wy);
            }
        }
    }
    // pin compiler order: no cvt-phase reads may hoist above the atomics
    __builtin_amdgcn_sched_barrier(0);

    // ============ Phase 3.5: own strip f32 -> bf16 in place (wave-local) ===
    {
        float* strip = &Am[wq * 132];
        const int row = lane >> 2, cc = (lane & 3) * 32;
        float vreg[32];
        #pragma unroll
        for (int u = 0; u < 8; ++u) {
            const f32x4 vv = *(const f32x4*)&strip[row * 132 + cc + 4 * u];
            vreg[4 * u + 0] = vv[0]; vreg[4 * u + 1] = vv[1];
            vreg[4 * u + 2] = vv[2]; vreg[4 * u + 3] = vv[3];
        }
        // all strip reads (all lanes) precede all strip writes
        __builtin_amdgcn_sched_barrier(0);
        short* sb = (short*)strip;                  // bf16 strip, stride 136
        #pragma unroll
        for (int u = 0; u < 4; ++u) {
            s16x8 o;
            #pragma unroll
            for (int j = 0; j < 8; ++j) o[j] = (short)f2bf(vreg[u * 8 + j]);
            *(s16x8*)&sb[row * 136 + cc + u * 8] = o;
        }
    }
    __builtin_amdgcn_sched_barrier(0);   // AV reads stay below cvt writes

    // ============ Phase 4: AV MFMA on own strip + pair-mean + residual =====
    {
        const short* sb = (const short*)&Am[wq * 132];
        f32x4 oacc[2] = {};
        #pragma unroll
        for (int ks = 0; ks < 4; ++ks) {
            const s16x8 af = *(const s16x8*)&sb[col * 136 + ks * 32 + quad * 8];
            #pragma unroll
            for (int n2 = 0; n2 < 2; ++n2) {
                const s16x8 bv = *(const s16x8*)&VTl[(n2 * 16 + col) * 136
                                                     + ks * 32 + quad * 8];
                oacc[n2] = __builtin_amdgcn_mfma_f32_16x16x32_bf16(af, bv, oacc[n2], 0, 0, 0);
            }
        }
        #pragma unroll
        for (int n2 = 0; n2 < 2; ++n2) {
            const int d = h * 32 + n2 * 16 + col;
            #pragma unroll
            for (int pr = 0; pr < 2; ++pr) {
                const float avg = 0.5f * (oacc[n2][2 * pr] + oacc[n2][2 * pr + 1]);
                const int pj = wave * 8 + quad * 2 + pr;
                const size_t re = ((size_t)b * 64 + pj) * 256 + d;
                const size_t ro = ((size_t)b * 64 + pj + 32) * 256 + d;
                out[re] = query[re] + avg;
                out[ro] = query[ro] + avg;
            }
        }
    }
}

extern "C" void kernel_launch(void* const* d_in, const int* in_sizes, int n_in,
                              void* d_out, int out_size, void* d_ws, size_t ws_size,
                              hipStream_t stream) {
    (void)in_sizes; (void)n_in; (void)out_size; (void)ws_size;
    const float* query      = (const float*)d_in[0];
    const float* key_hist   = (const float*)d_in[1];
    const float* value_hist = (const float*)d_in[2];
    const float* refp       = (const float*)d_in[3];
    const float* W_off      = (const float*)d_in[5];
    const float* b_off      = (const float*)d_in[6];

    char* ws = (char*)d_ws;
    short* Wtb = (short*)(ws);                 // 1 MB
    short* Qb  = (short*)(ws + (1u << 20));    // 2 MB
    short* Khb = (short*)(ws + (3u << 20));    // 2 MB
    float* out = (float*)d_out;

    prep<<<2560, 256, 0, stream>>>(W_off, query, key_hist, Wtb, Qb, Khb);
    mega3<<<dim3(8, 64), 256, 0, stream>>>(query, value_hist, refp,
                                           Qb, Khb, Wtb, b_off, out);
}

// Round 2
// 165.731 us; speedup vs baseline: 1.1046x; 1.1046x over previous
//
#include <hip/hip_runtime.h>

// Problem constants (hardcoded; spatial_shapes = [[4,8]]*4)
//  bs=64, nq=64, E=256, Hn=8, dh=32, L=4, P=16, BEV=2, Pb=32
//  qb=128 collapses to 64. OFF col (h,f,c)=h*256+2f+c; rp level = f&3;
//  image level = f>>5 = wave; attn key = f; output pairs (2q,2q+1) -> pj/pj+32.
//
// ws: [0,1M) Wtb bf16 [2048][256] | [1M,3M) Qb bf16 [4096][256]
//     [3M,5M) Khb bf16 [4096][256]
//
// mega4 (this round): N-split GEMM (wave owns n' quarter -> its own level),
// B-frags DIRECT from Wtb in L2 (no redundancy, no Bsl staging, no staging
// barriers). Scatter topology = mega2 (wave w writes Am columns of level w
// only -> no cross-wave collisions). Separate Amb buffer kills the cvt
// read/write barrier. 3 barriers total. LDS 79360 B = 2 blocks/CU (grid is
// 512 blocks -> 2/CU is the hard cap anyway, so VGPRs are free: lb(256,2)).

typedef short  s16x8 __attribute__((ext_vector_type(8)));
typedef short  s16x4 __attribute__((ext_vector_type(4)));
typedef float  f32x4 __attribute__((ext_vector_type(4)));

__device__ __forceinline__ unsigned short f2bf(float f) {
    union { float f; unsigned u; } v; v.f = f;
    unsigned r = v.u + 0x7FFFu + ((v.u >> 16) & 1u);   // RNE
    return (unsigned short)(r >> 16);
}
__device__ __forceinline__ float bf2f(unsigned short u) {
    return __uint_as_float(((unsigned)u) << 16);
}

// ---------------------------------------------------------------------------
// prep: [0,512) W transpose f32->bf16 ; [512,1536) query->Qb ;
//       [1536,2560) key_hist->Khb   (unchanged, verified)
// ---------------------------------------------------------------------------
__global__ __launch_bounds__(256) void prep(
    const float* __restrict__ W, const float* __restrict__ query,
    const float* __restrict__ key_hist,
    short* __restrict__ Wtb, short* __restrict__ Qb, short* __restrict__ Khb)
{
    __shared__ float s[32][33];
    const int bx = blockIdx.x, t = threadIdx.x;
    if (bx < 512) {
        const int n0 = (bx & 63) * 32, k0 = (bx >> 6) * 32;
        const int c = t & 31, r0 = t >> 5;
        #pragma unroll
        for (int p = 0; p < 4; ++p) {
            const int r = r0 + p * 8;
            s[r][c] = W[(size_t)(k0 + r) * 2048 + n0 + c];
        }
        __syncthreads();
        #pragma unroll
        for (int p = 0; p < 4; ++p) {
            const int r = r0 + p * 8;
            Wtb[(size_t)(n0 + r) * 256 + k0 + c] = (short)f2bf(s[c][r]);
        }
    } else {
        const int j = bx - 512;
        const bool isK = j >= 1024;
        const float* src = isK ? key_hist : query;
        short* dst = isK ? Khb : Qb;
        const int i4 = ((j & 1023) * 256 + t) * 4;
        const float4 v = *(const float4*)(src + i4);
        s16x4 o;
        o.x = (short)f2bf(v.x); o.y = (short)f2bf(v.y);
        o.z = (short)f2bf(v.z); o.w = (short)f2bf(v.w);
        *(s16x4*)(dst + i4) = o;
    }
}

// ---------------------------------------------------------------------------
// mega4: one block per (h,b). LDS 79360 B -> 2 blocks/CU. 3 barriers.
// ---------------------------------------------------------------------------
__global__ __launch_bounds__(256, 2) void mega4(
    const float* __restrict__ query, const float* __restrict__ value_hist,
    const float* __restrict__ refp,
    const short* __restrict__ Qb, const short* __restrict__ Khb,
    const short* __restrict__ Wtb, const float* __restrict__ bias,
    float* __restrict__ out)
{
    const int h = blockIdx.x, b = blockIdx.y;
    const int t = threadIdx.x, lane = t & 63, wave = t >> 6;
    const int quad = lane >> 4, col = lane & 15;
    const int wq = wave * 16;

    __shared__ __align__(16) short VTl[32 * 136];   // V^T [d][p], 8704 B
    __shared__ __align__(16) short attLb[64 * 136]; // att probs bf16, 17408 B
    __shared__ __align__(16) float rpsL[512];       // refp rows, 2048 B
    __shared__ __align__(16) float Am[64 * 132];    // scatter acc f32, 33792 B
    __shared__ __align__(16) short Amb[64 * 136];   // scatter acc bf16, 17408 B

    // ============ Phase A: everything before the first barrier ============
    // A1: stage VTl (values = [query rows | value_hist rows], h-slice, ^T)
    {
        const int p = t >> 1, hf = (t & 1) * 16;
        const float* src = ((p < 64) ? query : value_hist) +
                           (size_t)(b * 64 + (p & 63)) * 256 + h * 32 + hf;
        #pragma unroll
        for (int u = 0; u < 4; ++u) {
            const float4 v = *(const float4*)(src + 4 * u);
            VTl[(hf + 4 * u + 0) * 136 + p] = (short)f2bf(v.x);
            VTl[(hf + 4 * u + 1) * 136 + p] = (short)f2bf(v.y);
            VTl[(hf + 4 * u + 2) * 136 + p] = (short)f2bf(v.z);
            VTl[(hf + 4 * u + 3) * 136 + p] = (short)f2bf(v.w);
        }
    }
    // A2: refp rows + zero Am
    rpsL[t]       = refp[(size_t)b * 512 + t];
    rpsL[t + 256] = refp[(size_t)b * 512 + t + 256];
    #pragma unroll
    for (int u = 0; u < 33; ++u) Am[t + 256 * u] = 0.f;

    // A3: offsets GEMM, N-split: wave owns n' in [64*wave, +64).
    //     acc[mi][nj]; q = 16mi+4quad+reg, n' = 64*wave + 16nj + col.
    //     A-frags direct from Qb (L2), B-frags DIRECT from Wtb (L2) —
    //     each wave's B-quarter is distinct: no redundancy, no staging.
    f32x4 acc[4][4] = {};
    #pragma unroll
    for (int kq = 0; kq < 4; ++kq) {
        s16x8 afp[4][2], bfp[4][2];
        #pragma unroll
        for (int mi = 0; mi < 4; ++mi)
            #pragma unroll
            for (int ks = 0; ks < 2; ++ks)
                afp[mi][ks] = *(const s16x8*)(Qb +
                    ((size_t)b * 64 + 16 * mi + col) * 256
                    + kq * 64 + ks * 32 + quad * 8);
        #pragma unroll
        for (int nj = 0; nj < 4; ++nj)
            #pragma unroll
            for (int ks = 0; ks < 2; ++ks)
                bfp[nj][ks] = *(const s16x8*)(Wtb +
                    ((size_t)(h * 256 + wave * 64 + 16 * nj + col)) * 256
                    + kq * 64 + ks * 32 + quad * 8);
        #pragma unroll
        for (int ks = 0; ks < 2; ++ks)
            #pragma unroll
            for (int mi = 0; mi < 4; ++mi)
                #pragma unroll
                for (int nj = 0; nj < 4; ++nj)
                    acc[mi][nj] = __builtin_amdgcn_mfma_f32_16x16x32_bf16(
                        afp[mi][ks], bfp[nj][ks], acc[mi][nj], 0, 0, 0);
    }

    // A4: logits + softmax -> attLb (wave's q-strip rows)
    {
        const s16x8 aq = *(const s16x8*)(Qb +
            ((size_t)b * 64 + wq + col) * 256 + h * 32 + quad * 8);
        f32x4 lacc[8];
        #pragma unroll
        for (int t8 = 0; t8 < 8; ++t8) {
            const short* src = (t8 < 4)
                ? (Qb  + ((size_t)b * 64 + 16 * t8 + col) * 256)
                : (Khb + ((size_t)b * 64 + 16 * (t8 - 4) + col) * 256);
            const s16x8 bk = *(const s16x8*)(src + h * 32 + quad * 8);
            const f32x4 z = {0.f, 0.f, 0.f, 0.f};
            lacc[t8] = __builtin_amdgcn_mfma_f32_16x16x32_bf16(aq, bk, z, 0, 0, 0);
        }
        #pragma unroll
        for (int r = 0; r < 4; ++r) {
            float m = lacc[0][r];
            #pragma unroll
            for (int t8 = 1; t8 < 8; ++t8) m = fmaxf(m, lacc[t8][r]);
            #pragma unroll
            for (int s = 1; s < 16; s <<= 1) m = fmaxf(m, __shfl_xor(m, s, 64));
            float e[8], ssum = 0.f;
            #pragma unroll
            for (int t8 = 0; t8 < 8; ++t8) {
                e[t8] = __expf(lacc[t8][r] - m); ssum += e[t8];
            }
            #pragma unroll
            for (int s = 1; s < 16; s <<= 1) ssum += __shfl_xor(ssum, s, 64);
            const float inv = 1.0f / ssum;
            const int q = wq + 4 * quad + r;
            #pragma unroll
            for (int t8 = 0; t8 < 8; ++t8)
                attLb[q * 136 + 16 * t8 + col] = (short)f2bf(e[t8] * inv);
        }
    }

    // A5: bias prefetch for this wave's n' columns
    float bjv[4];
    #pragma unroll
    for (int nj = 0; nj < 4; ++nj)
        bjv[nj] = bias[h * 256 + wave * 64 + 16 * nj + col];

    __syncthreads();   // B1: VTl, rpsL, Am-zero, attLb all visible

    // ============ Phase B: bilinear scatter (wave w -> level w cols) =======
    {
        const int i   = col >> 1;          // f-sub 0..7 ; rp level = i&3
        const int par = col & 1;           // 0: x-coords, 1: y-coords
        const int base = 32 * wave;        // image level = f>>5 = wave
        #pragma unroll
        for (int nj = 0; nj < 4; ++nj) {
            const int f = 32 * wave + 8 * nj + i;
            #pragma unroll
            for (int mi = 0; mi < 4; ++mi) {
                float v[4], p[4];
                #pragma unroll
                for (int r = 0; r < 4; ++r) v[r] = acc[mi][nj][r] + bjv[nj];
                #pragma unroll
                for (int r = 0; r < 4; ++r) p[r] = __shfl_xor(v[r], 1, 64);
                #pragma unroll
                for (int rs = 0; rs < 2; ++rs) {
                    const int r = par * 2 + rs;
                    const float ox = par ? p[r] : v[r];
                    const float oy = par ? v[r] : p[r];
                    const int q = 16 * mi + 4 * quad + r;
                    const float2 rp = *(const float2*)&rpsL[q * 8 + (i & 3) * 2];
                    const float a = bf2f((unsigned short)attLb[q * 136 + f]);
                    const float gx = 8.f * (rp.x + ox * 0.125f) - 0.5f;
                    const float gy = 4.f * (rp.y + oy * 0.25f) - 0.5f;
                    const float x0f = floorf(gx), y0f = floorf(gy);
                    const float wx = gx - x0f, wy = gy - y0f;
                    const int x0 = (int)x0f, y0 = (int)y0f;
                    float* rowW = &Am[q * 132 + base];
                    const bool xv0 = (x0 >= 0) && (x0 < 8);
                    const bool xv1 = (x0 >= -1) && (x0 < 7);
                    const bool yv0 = (y0 >= 0) && (y0 < 4);
                    const bool yv1 = (y0 >= -1) && (y0 < 3);
                    if (xv0 && yv0) unsafeAtomicAdd(&rowW[y0 * 8 + x0],           a * (1.f - wx) * (1.f - wy));
                    if (xv1 && yv0) unsafeAtomicAdd(&rowW[y0 * 8 + x0 + 1],       a * wx * (1.f - wy));
                    if (xv0 && yv1) unsafeAtomicAdd(&rowW[(y0 + 1) * 8 + x0],     a * (1.f - wx) * wy);
                    if (xv1 && yv1) unsafeAtomicAdd(&rowW[(y0 + 1) * 8 + x0 + 1], a * wx * wy);
                }
            }
        }
    }
    __syncthreads();   // B2: scatter complete

    // ============ Phase C: Am(f32) -> Amb(bf16), separate buffers ==========
    {
        const int cq = t >> 2, cc = (t & 3) * 32;
        #pragma unroll
        for (int u = 0; u < 4; ++u) {
            const f32x4 v0 = *(const f32x4*)&Am[cq * 132 + cc + 8 * u];
            const f32x4 v1 = *(const f32x4*)&Am[cq * 132 + cc + 8 * u + 4];
            s16x8 o;
            o[0] = (short)f2bf(v0[0]); o[1] = (short)f2bf(v0[1]);
            o[2] = (short)f2bf(v0[2]); o[3] = (short)f2bf(v0[3]);
            o[4] = (short)f2bf(v1[0]); o[5] = (short)f2bf(v1[1]);
            o[6] = (short)f2bf(v1[2]); o[7] = (short)f2bf(v1[3]);
            *(s16x8*)&Amb[cq * 136 + cc + u * 8] = o;
        }
    }
    __syncthreads();   // B3: Amb ready

    // ============ Phase D: AV MFMA + pair-mean + residual ==================
    {
        f32x4 oacc[2] = {};
        #pragma unroll
        for (int ks = 0; ks < 4; ++ks) {
            const s16x8 af = *(const s16x8*)&Amb[(wq + col) * 136 + ks * 32 + quad * 8];
            #pragma unroll
            for (int n2 = 0; n2 < 2; ++n2) {
                const s16x8 bv = *(const s16x8*)&VTl[(n2 * 16 + col) * 136
                                                     + ks * 32 + quad * 8];
                oacc[n2] = __builtin_amdgcn_mfma_f32_16x16x32_bf16(af, bv, oacc[n2], 0, 0, 0);
            }
        }
        #pragma unroll
        for (int n2 = 0; n2 < 2; ++n2) {
            const int d = h * 32 + n2 * 16 + col;
            #pragma unroll
            for (int pr = 0; pr < 2; ++pr) {
                const float avg = 0.5f * (oacc[n2][2 * pr] + oacc[n2][2 * pr + 1]);
                const int pj = wave * 8 + quad * 2 + pr;
                const size_t re = ((size_t)b * 64 + pj) * 256 + d;
                const size_t ro = ((size_t)b * 64 + pj + 32) * 256 + d;
                out[re] = query[re] + avg;
                out[ro] = query[ro] + avg;
            }
        }
    }
}

extern "C" void kernel_launch(void* const* d_in, const int* in_sizes, int n_in,
                              void* d_out, int out_size, void* d_ws, size_t ws_size,
                              hipStream_t stream) {
    (void)in_sizes; (void)n_in; (void)out_size; (void)ws_size;
    const float* query      = (const float*)d_in[0];
    const float* key_hist   = (const float*)d_in[1];
    const float* value_hist = (const float*)d_in[2];
    const float* refp       = (const float*)d_in[3];
    const float* W_off      = (const float*)d_in[5];
    const float* b_off      = (const float*)d_in[6];

    char* ws = (char*)d_ws;
    short* Wtb = (short*)(ws);                 // 1 MB
    short* Qb  = (short*)(ws + (1u << 20));    // 2 MB
    short* Khb = (short*)(ws + (3u << 20));    // 2 MB
    float* out = (float*)d_out;

    prep<<<2560, 256, 0, stream>>>(W_off, query, key_hist, Wtb, Qb, Khb);
    mega4<<<dim3(8, 64), 256, 0, stream>>>(query, value_hist, refp,
                                           Qb, Khb, Wtb, b_off, out);
}